// Round 2
// baseline (1419.880 us; speedup 1.0000x reference)
//
#include <hip/hip_runtime.h>

// ---------------------------------------------------------------------------
// SpatialAttention, N=8192, D=H=512, GAMMA=0.5
//   S = exp(maskR ? -inf : QrKr^T/sqrt(H)) + 0.5*exp(maskF ? -inf : QfKf^T/sqrt(H))
//   attn = S / rowsum(S);  cntx = attn @ (x Wv + bv)
// d_out = [cntx (N*D f32) | attn (N*N f32)]
//
// R2: fused dual-branch scores kernel with global_load_lds double-buffered
// 2-phase prefetch (m248 template), coalesced attn stores via LDS restage,
// cntx consumes unnormalized attn scaled by inv[row], norm runs last.
// ---------------------------------------------------------------------------

#define K_N 8192
#define K_D 512

typedef float  f32x4 __attribute__((ext_vector_type(4)));
typedef _Float16 f16x8 __attribute__((ext_vector_type(8)));
typedef unsigned short u16;

__device__ __forceinline__ u16 f2h(float f) {
  _Float16 h = (_Float16)f;
  return __builtin_bit_cast(u16, h);
}

__device__ __forceinline__ void gload_lds16(const void* g, void* l) {
  __builtin_amdgcn_global_load_lds(
      (const __attribute__((address_space(1))) void*)g,
      (__attribute__((address_space(3))) void*)l, 16, 0, 0);
}

// ---------------------------------------------------------------------------
// Mask dtype detector (1-byte bool vs 4-byte): bytes at offset%4==1 are all 0
// for 4-byte 0/1 data, ~half nonzero for byte masks.
// ---------------------------------------------------------------------------
__global__ void k_detect(const unsigned char* __restrict__ m, int* __restrict__ flag) {
  __shared__ int any;
  if (threadIdx.x == 0) any = 0;
  __syncthreads();
  int local = 0;
  for (int i = threadIdx.x; i < 65536; i += 256)
    local |= m[4 * i + 1];
  if (local) atomicOr(&any, 1);
  __syncthreads();
  if (threadIdx.x == 0) *flag = any ? 1 : 0;
}

__device__ __forceinline__ bool mask_at(const void* mask, int mode, size_t idx) {
  if (mode) return ((const unsigned char*)mask)[idx] != 0;
  return ((const int*)mask)[idx] != 0;
}

// ---------------------------------------------------------------------------
__global__ void k_cvt_x(const float* __restrict__ x, u16* __restrict__ xh) {
  int i = blockIdx.x * 256 + threadIdx.x;
  float4 v = ((const float4*)x)[i];
  ushort4 o;
  o.x = f2h(v.x); o.y = f2h(v.y); o.z = f2h(v.z); o.w = f2h(v.w);
  ((ushort4*)xh)[i] = o;
}

template <int IN_F32>
__global__ void k_transpose(const void* __restrict__ in, u16* __restrict__ out,
                            int R, int C) {
  __shared__ u16 sm[64][65];
  int c0 = blockIdx.x * 64, r0 = blockIdx.y * 64;
#pragma unroll
  for (int e = 0; e < 16; e++) {
    int idx = e * 256 + threadIdx.x;
    int i = idx >> 6, j = idx & 63;
    u16 h;
    if (IN_F32) h = f2h(((const float*)in)[(size_t)(r0 + i) * C + c0 + j]);
    else        h = ((const u16*)in)[(size_t)(r0 + i) * C + c0 + j];
    sm[i][j] = h;
  }
  __syncthreads();
#pragma unroll
  for (int e = 0; e < 16; e++) {
    int idx = e * 256 + threadIdx.x;
    int j = idx >> 6, i = idx & 63;
    out[(size_t)(c0 + j) * R + r0 + i] = sm[i][j];
  }
}

// ---------------------------------------------------------------------------
// Reg-staged GEMM core (kept for proj & cntx): C(128x128) += A(128xK)*Bt^T
// ---------------------------------------------------------------------------
template <int A_F32>
__device__ __forceinline__ void gemm_core(const void* __restrict__ Ap, int lda,
                                          const u16* __restrict__ Bt, int ldb,
                                          int rowBase, int colBase, int K,
                                          u16* sA, u16* sB, f32x4 (&acc)[4][4],
                                          const float* __restrict__ ascale) {
  const int tid   = threadIdx.x;
  const int lane  = tid & 63;
  const int waveM = tid >> 7;
  const int waveN = (tid >> 6) & 1;
  const int lrow  = lane & 15;
  const int lk    = lane >> 4;

  for (int k0 = 0; k0 < K; k0 += 64) {
    __syncthreads();
#pragma unroll
    for (int g = 0; g < 4; g++) {
      int cid = g * 256 + tid;
      int row = cid >> 3;
      int pk  = cid & 7;
      int k16 = pk ^ (row & 7);
      if (A_F32) {
        const float* s = (const float*)Ap + (size_t)(rowBase + row) * lda + k0 + k16 * 8;
        float4 v0 = *(const float4*)s;
        float4 v1 = *(const float4*)(s + 4);
        ushort4 h0, h1;
        h0.x = f2h(v0.x); h0.y = f2h(v0.y); h0.z = f2h(v0.z); h0.w = f2h(v0.w);
        h1.x = f2h(v1.x); h1.y = f2h(v1.y); h1.z = f2h(v1.z); h1.w = f2h(v1.w);
        *(ushort4*)&sA[cid * 8]     = h0;
        *(ushort4*)&sA[cid * 8 + 4] = h1;
      } else {
        uint4 v = *(const uint4*)((const u16*)Ap + (size_t)(rowBase + row) * lda + k0 + k16 * 8);
        *(uint4*)&sA[cid * 8] = v;
      }
      uint4 w = *(const uint4*)(Bt + (size_t)(colBase + row) * ldb + k0 + k16 * 8);
      *(uint4*)&sB[cid * 8] = w;
    }
    __syncthreads();
#pragma unroll
    for (int kk = 0; kk < 2; kk++) {
      f16x8 af[4], bfv[4];
      int k16 = kk * 4 + lk;
#pragma unroll
      for (int mb = 0; mb < 4; mb++) {
        int r = waveM * 64 + mb * 16 + lrow;
        af[mb] = *(const f16x8*)&sA[r * 64 + ((k16 ^ (r & 7)) << 3)];
      }
#pragma unroll
      for (int nb = 0; nb < 4; nb++) {
        int c = waveN * 64 + nb * 16 + lrow;
        bfv[nb] = *(const f16x8*)&sB[c * 64 + ((k16 ^ (c & 7)) << 3)];
      }
#pragma unroll
      for (int mb = 0; mb < 4; mb++)
#pragma unroll
        for (int nb = 0; nb < 4; nb++)
          acc[mb][nb] = __builtin_amdgcn_mfma_f32_16x16x32_f16(af[mb], bfv[nb], acc[mb][nb], 0, 0, 0);
    }
  }
  (void)ascale;
}

// ---------------------------------------------------------------------------
// Projections: z=0..3 -> Q_r,K_r,Q_f,K_f; z=4 -> V=x@Wv+bv (all fp16)
// ---------------------------------------------------------------------------
__global__ __launch_bounds__(256) void k_proj(const u16* __restrict__ xh,
                                              const u16* __restrict__ wt,
                                              u16* __restrict__ qr, u16* __restrict__ kr,
                                              u16* __restrict__ qf, u16* __restrict__ kf,
                                              u16* __restrict__ vh,
                                              const float* __restrict__ bv) {
  __shared__ u16 sA[128 * 64], sB[128 * 64];
  f32x4 acc[4][4] = {};
  const int z = blockIdx.z;
  const int rowBase = blockIdx.y * 128, colBase = blockIdx.x * 128;
  gemm_core<0>(xh, K_D, wt + (size_t)z * 262144, K_D, rowBase, colBase, K_D, sA, sB, acc, nullptr);

  u16* out = (z == 0) ? qr : (z == 1) ? kr : (z == 2) ? qf : (z == 3) ? kf : vh;
  const int lane = threadIdx.x & 63;
  const int waveM = threadIdx.x >> 7, waveN = (threadIdx.x >> 6) & 1;
  const int lrow = lane & 15, lk = lane >> 4;
#pragma unroll
  for (int mb = 0; mb < 4; mb++)
#pragma unroll
    for (int nb = 0; nb < 4; nb++)
#pragma unroll
      for (int r = 0; r < 4; r++) {
        int grow = rowBase + waveM * 64 + mb * 16 + lk * 4 + r;
        int gcol = colBase + waveN * 64 + nb * 16 + lrow;
        float v = acc[mb][nb][r];
        if (z == 4) v += bv[gcol];
        out[(size_t)grow * K_D + gcol] = f2h(v);
      }
}

// ---------------------------------------------------------------------------
// Fused dual-branch scores: attn = exp_r + 0.5*exp_f (unnormalized) + partials.
// 2-phase global_load_lds prefetch, dbuf LDS 128 KB, 4 tensors staged.
// ---------------------------------------------------------------------------
__global__ __launch_bounds__(256, 1) void k_scores_fused(
    const u16* __restrict__ qr, const u16* __restrict__ kr,
    const u16* __restrict__ qf, const u16* __restrict__ kf,
    const void* __restrict__ mR, const void* __restrict__ mF,
    const int* __restrict__ flag,
    float* __restrict__ attn, float* __restrict__ partial) {

  __shared__ u16 s[2][4][8192];   // [dbuf][Qr,Kr,Qf,Kf][128*64]  = 128 KiB

  const int tid = threadIdx.x;
  const int lane = tid & 63, wave = tid >> 6;
  const int rowBase = blockIdx.y * 128, colBase = blockIdx.x * 128;

  const u16* base0 = qr + (size_t)rowBase * K_D;
  const u16* base1 = kr + (size_t)colBase * K_D;
  const u16* base2 = qf + (size_t)rowBase * K_D;
  const u16* base3 = kf + (size_t)colBase * K_D;

  f32x4 accR[4][4] = {}, accF[4][4] = {};

  auto STAGE = [&](int b, int k0) {
    const u16* bases[4] = {base0, base1, base2, base3};
#pragma unroll
    for (int t = 0; t < 4; ++t)
#pragma unroll
      for (int j = 0; j < 4; ++j) {
        int cid = (wave * 4 + j) * 64 + lane;
        int row = cid >> 3;
        int k16 = (cid & 7) ^ (row & 7);   // swizzled source -> linear LDS
        gload_lds16(bases[t] + (size_t)row * K_D + k0 + k16 * 8,
                    &s[b][t][(wave * 4 + j) * 512]);
      }
  };

  STAGE(0, 0);
  __syncthreads();

  const int waveM = tid >> 7, waveN = (tid >> 6) & 1;
  const int lrow = lane & 15, lk = lane >> 4;

  int cur = 0;
  for (int it = 0; it < 8; ++it) {
    if (it < 7) STAGE(cur ^ 1, (it + 1) * 64);   // prefetch next K-tile
#pragma unroll
    for (int kk = 0; kk < 2; ++kk) {
      int k16 = kk * 4 + lk;
      f16x8 aR[4], bR[4], aF[4], bF[4];
#pragma unroll
      for (int mb = 0; mb < 4; ++mb) {
        int r = waveM * 64 + mb * 16 + lrow;
        int off = r * 64 + ((k16 ^ (r & 7)) << 3);
        aR[mb] = *(const f16x8*)&s[cur][0][off];
        aF[mb] = *(const f16x8*)&s[cur][2][off];
      }
#pragma unroll
      for (int nb = 0; nb < 4; ++nb) {
        int c = waveN * 64 + nb * 16 + lrow;
        int off = c * 64 + ((k16 ^ (c & 7)) << 3);
        bR[nb] = *(const f16x8*)&s[cur][1][off];
        bF[nb] = *(const f16x8*)&s[cur][3][off];
      }
#pragma unroll
      for (int mb = 0; mb < 4; ++mb)
#pragma unroll
        for (int nb = 0; nb < 4; ++nb) {
          accR[mb][nb] = __builtin_amdgcn_mfma_f32_16x16x32_f16(aR[mb], bR[nb], accR[mb][nb], 0, 0, 0);
          accF[mb][nb] = __builtin_amdgcn_mfma_f32_16x16x32_f16(aF[mb], bF[nb], accF[mb][nb], 0, 0, 0);
        }
    }
    __syncthreads();   // drains vmcnt: next tile resident; cur free to overwrite
    cur ^= 1;
  }

  // ---- epilogue: masked exp, rowsum partials, coalesced store via LDS ----
  const float scale = 0.04419417382415922f;   // 1/sqrt(512)
  const int mode = *flag;
  float* vt = (float*)&s[0][0][0];            // 128 x 132 f32 restage tile

#pragma unroll
  for (int mb = 0; mb < 4; ++mb)
#pragma unroll
    for (int r = 0; r < 4; ++r) {
      int growl = waveM * 64 + mb * 16 + lk * 4 + r;
      int grow = rowBase + growl;
      float rs = 0.f;
#pragma unroll
      for (int nb = 0; nb < 4; ++nb) {
        int gcoll = waveN * 64 + nb * 16 + lrow;
        size_t oi = (size_t)grow * K_N + colBase + gcoll;
        bool m1 = mask_at(mR, mode, oi);
        bool m2 = mask_at(mF, mode, oi);
        float er = m1 ? 0.f : __expf(accR[mb][nb][r] * scale);
        float ef = m2 ? 0.f : __expf(accF[mb][nb][r] * scale);
        float v = er + 0.5f * ef;
        rs += v;
        vt[growl * 132 + gcoll] = v;
      }
      rs += __shfl_xor(rs, 1, 64);
      rs += __shfl_xor(rs, 2, 64);
      rs += __shfl_xor(rs, 4, 64);
      rs += __shfl_xor(rs, 8, 64);
      if (lrow == 0)
        partial[(size_t)grow * 128 + blockIdx.x * 2 + waveN] = rs;
    }
  __syncthreads();

#pragma unroll
  for (int j = 0; j < 16; ++j) {
    int f = j * 256 + tid;          // float4 id within 128x128 tile
    int row = f >> 5, c4 = f & 31;
    float4 val = *(const float4*)&vt[row * 132 + c4 * 4];
    *(float4*)&attn[(size_t)(rowBase + row) * K_N + colBase + c4 * 4] = val;
  }
}

// ---------------------------------------------------------------------------
__global__ void k_rowsum(const float* __restrict__ partial, float* __restrict__ inv) {
  int r = blockIdx.x * 256 + threadIdx.x;
  const float* p = partial + (size_t)r * 128;
  float s = 0.f;
#pragma unroll 8
  for (int j = 0; j < 128; j++) s += p[j];
  inv[r] = 1.0f / s;
}

__global__ void k_norm(float* __restrict__ attn, const float* __restrict__ inv) {
  const size_t total = (size_t)K_N * K_N / 4;
  for (size_t i = (size_t)blockIdx.x * 256 + threadIdx.x; i < total;
       i += (size_t)gridDim.x * 256) {
    int row = (int)(i >> 11);
    float s = inv[row];
    float4 v = ((float4*)attn)[i];
    v.x *= s; v.y *= s; v.z *= s; v.w *= s;
    ((float4*)attn)[i] = v;
  }
}

// ---------------------------------------------------------------------------
// cntx = (unnormalized attn * inv[row]) @ V, XCD-swizzled so the 4 col-blocks
// sharing an attn row-panel land on one XCD's L2.
// ---------------------------------------------------------------------------
__global__ __launch_bounds__(256) void k_cntx(const float* __restrict__ attn,
                                              const u16* __restrict__ vT,
                                              const float* __restrict__ inv,
                                              float* __restrict__ out) {
  __shared__ u16 sA[128 * 64], sB[128 * 64];
  f32x4 acc[4][4] = {};
  int b = blockIdx.x + blockIdx.y * 4;   // hw linear id; b%8 ~ XCD
  int c = b & 7, jj = b >> 3;
  int xb = jj & 3, yb = c + 8 * (jj >> 2);
  const int rowBase = yb * 128, colBase = xb * 128;
  gemm_core<1>(attn, K_N, vT, K_N, rowBase, colBase, K_N, sA, sB, acc, nullptr);

  const int lane = threadIdx.x & 63;
  const int waveM = threadIdx.x >> 7, waveN = (threadIdx.x >> 6) & 1;
  const int lrow = lane & 15, lk = lane >> 4;
#pragma unroll
  for (int mb = 0; mb < 4; mb++)
#pragma unroll
    for (int r = 0; r < 4; r++) {
      int grow = rowBase + waveM * 64 + mb * 16 + lk * 4 + r;
      float iv = inv[grow];
#pragma unroll
      for (int nb = 0; nb < 4; nb++) {
        int gcol = colBase + waveN * 64 + nb * 16 + lrow;
        out[(size_t)grow * K_D + gcol] = acc[mb][nb][r] * iv;
      }
    }
}

// ---------------------------------------------------------------------------
extern "C" void kernel_launch(void* const* d_in, const int* in_sizes, int n_in,
                              void* d_out, int out_size, void* d_ws, size_t ws_size,
                              hipStream_t stream) {
  const float* x   = (const float*)d_in[0];
  const void*  mR  = d_in[1];
  const void*  mF  = d_in[2];
  const float* Wv  = (const float*)d_in[7];
  const float* bv  = (const float*)d_in[8];

  const size_t ND = (size_t)K_N * K_D;
  u16* xh = (u16*)d_ws;
  u16* qr = xh + ND;
  u16* kr = qr + ND;
  u16* qf = kr + ND;
  u16* kf = qf + ND;
  u16* vh = kf + ND;
  u16* vT = vh + ND;
  u16* wt = vT + ND;              // 5 * 512*512 fp16

  float* cntx = (float*)d_out;
  float* attn = cntx + ND;
  // partial/inv overlay xh (dead after k_proj); flag in cntx (written last)
  float* partial = (float*)d_ws;                 // [8192][128]
  float* inv     = partial + (size_t)K_N * 128;  // [8192]
  int*   flag    = (int*)cntx;

  k_detect<<<1, 256, 0, stream>>>((const unsigned char*)mR, flag);
  k_cvt_x<<<4096, 256, 0, stream>>>(x, xh);

  k_transpose<1><<<dim3(8, 8), 256, 0, stream>>>((const void*)d_in[3], wt + 0 * 262144, 512, 512);
  k_transpose<1><<<dim3(8, 8), 256, 0, stream>>>((const void*)d_in[4], wt + 1 * 262144, 512, 512);
  k_transpose<1><<<dim3(8, 8), 256, 0, stream>>>((const void*)d_in[5], wt + 2 * 262144, 512, 512);
  k_transpose<1><<<dim3(8, 8), 256, 0, stream>>>((const void*)d_in[6], wt + 3 * 262144, 512, 512);
  k_transpose<1><<<dim3(8, 8), 256, 0, stream>>>(Wv,  wt + 4 * 262144, 512, 512);

  k_proj<<<dim3(4, 64, 5), 256, 0, stream>>>(xh, wt, qr, kr, qf, kf, vh, bv);
  k_transpose<0><<<dim3(8, 128), 256, 0, stream>>>(vh, vT, K_N, K_D);

  k_scores_fused<<<dim3(64, 64), 256, 0, stream>>>(qr, kr, qf, kf, mR, mF, flag, attn, partial);

  k_rowsum<<<32, 256, 0, stream>>>(partial, inv);
  k_cntx<<<dim3(4, 64), 256, 0, stream>>>(attn, vT, inv, cntx);
  k_norm<<<8192, 256, 0, stream>>>(attn, inv);
}

// Round 3
// 819.358 us; speedup vs baseline: 1.7329x; 1.7329x over previous
//
#include <hip/hip_runtime.h>

// ---------------------------------------------------------------------------
// SpatialAttention, N=8192, D=H=512, GAMMA=0.5
//   S = exp(maskR ? -inf : QrKr^T/sqrt(H)) + 0.5*exp(maskF ? -inf : QfKf^T/sqrt(H))
//   attn = S / rowsum(S);  cntx = attn @ (x Wv + bv)
// d_out = [cntx (N*D f32) | attn (N*N f32)]
//
// R3: masks bitpacked in a streaming prepass (512 MB int32 -> 16 MB bits);
// scores = 8-wave 128x128 dual-branch MFMA kernel writing fp16 unnormalized
// scores to ws scratch; norm reads fp16 + writes fp32 attn; cntx reads fp16.
// ws_size-guarded fallbacks: fp32-out / raw-mask paths.
// ---------------------------------------------------------------------------

#define K_N 8192
#define K_D 512

typedef float  f32x4 __attribute__((ext_vector_type(4)));
typedef _Float16 f16x8 __attribute__((ext_vector_type(8)));
typedef unsigned short u16;
typedef unsigned int u32;

__device__ __forceinline__ u16 f2h(float f) {
  _Float16 h = (_Float16)f;
  return __builtin_bit_cast(u16, h);
}
__device__ __forceinline__ float h2f(u16 b) {
  return (float)__builtin_bit_cast(_Float16, b);
}

__device__ __forceinline__ void gload_lds16(const void* g, void* l) {
  __builtin_amdgcn_global_load_lds(
      (const __attribute__((address_space(1))) void*)g,
      (__attribute__((address_space(3))) void*)l, 16, 0, 0);
}

// ---------------------------------------------------------------------------
// Mask dtype detector (1-byte bool vs 4-byte int/float): bytes at offset%4==1
// are all 0 for 4-byte 0/1 data, ~half nonzero for byte masks.
// ---------------------------------------------------------------------------
__global__ void k_detect(const unsigned char* __restrict__ m, int* __restrict__ flag) {
  __shared__ int any;
  if (threadIdx.x == 0) any = 0;
  __syncthreads();
  int local = 0;
  for (int i = threadIdx.x; i < 65536; i += 256)
    local |= m[4 * i + 1];
  if (local) atomicOr(&any, 1);
  __syncthreads();
  if (threadIdx.x == 0) *flag = any ? 1 : 0;
}

__device__ __forceinline__ bool mask_at(const void* mask, int mode, size_t idx) {
  if (mode) return ((const unsigned char*)mask)[idx] != 0;
  return ((const int*)mask)[idx] != 0;
}

// ---------------------------------------------------------------------------
// Bitpack both masks: word w = 32 consecutive elements; bit k = (elem != 0).
// ---------------------------------------------------------------------------
__device__ __forceinline__ u32 pack_one(const void* m, int mode, int w) {
  u32 r = 0;
  if (mode) {  // 1-byte elements: 32 B per word
    const uint4* p = (const uint4*)((const unsigned char*)m + (size_t)w * 32);
    uint4 a = p[0], b = p[1];
    u32 ws[8] = {a.x, a.y, a.z, a.w, b.x, b.y, b.z, b.w};
#pragma unroll
    for (int i = 0; i < 8; i++) {
      u32 v = ws[i];
      v |= v >> 4; v |= v >> 2; v |= v >> 1;
      v &= 0x01010101u;
      r |= (v & 1u) << (4 * i);
      r |= ((v >> 8) & 1u) << (4 * i + 1);
      r |= ((v >> 16) & 1u) << (4 * i + 2);
      r |= ((v >> 24) & 1u) << (4 * i + 3);
    }
  } else {     // 4-byte elements: 128 B per word
    const uint4* p = (const uint4*)((const int*)m + (size_t)w * 32);
#pragma unroll
    for (int i = 0; i < 8; i++) {
      uint4 v = p[i];
      r |= (v.x ? 1u : 0u) << (4 * i);
      r |= (v.y ? 1u : 0u) << (4 * i + 1);
      r |= (v.z ? 1u : 0u) << (4 * i + 2);
      r |= (v.w ? 1u : 0u) << (4 * i + 3);
    }
  }
  return r;
}

__global__ void k_packmask(const void* __restrict__ mR, const void* __restrict__ mF,
                           const int* __restrict__ flag,
                           u32* __restrict__ bR, u32* __restrict__ bF) {
  const int mode = *flag;
  const int W = (K_N / 32) * K_N;   // 2M words per mask
  for (int w = blockIdx.x * 256 + threadIdx.x; w < W; w += gridDim.x * 256) {
    bR[w] = pack_one(mR, mode, w);
    bF[w] = pack_one(mF, mode, w);
  }
}

// ---------------------------------------------------------------------------
__global__ void k_cvt_x(const float* __restrict__ x, u16* __restrict__ xh) {
  int i = blockIdx.x * 256 + threadIdx.x;
  float4 v = ((const float4*)x)[i];
  ushort4 o;
  o.x = f2h(v.x); o.y = f2h(v.y); o.z = f2h(v.z); o.w = f2h(v.w);
  ((ushort4*)xh)[i] = o;
}

template <int IN_F32>
__global__ void k_transpose(const void* __restrict__ in, u16* __restrict__ out,
                            int R, int C) {
  __shared__ u16 sm[64][65];
  int c0 = blockIdx.x * 64, r0 = blockIdx.y * 64;
#pragma unroll
  for (int e = 0; e < 16; e++) {
    int idx = e * 256 + threadIdx.x;
    int i = idx >> 6, j = idx & 63;
    u16 h;
    if (IN_F32) h = f2h(((const float*)in)[(size_t)(r0 + i) * C + c0 + j]);
    else        h = ((const u16*)in)[(size_t)(r0 + i) * C + c0 + j];
    sm[i][j] = h;
  }
  __syncthreads();
#pragma unroll
  for (int e = 0; e < 16; e++) {
    int idx = e * 256 + threadIdx.x;
    int j = idx >> 6, i = idx & 63;
    out[(size_t)(c0 + j) * R + r0 + i] = sm[i][j];
  }
}

// ---------------------------------------------------------------------------
// Reg-staged 4-wave GEMM core (proj & cntx): C(128x128) += A(128xK)*Bt^T
// ---------------------------------------------------------------------------
template <int A_F32>
__device__ __forceinline__ void gemm_core(const void* __restrict__ Ap, int lda,
                                          const u16* __restrict__ Bt, int ldb,
                                          int rowBase, int colBase, int K,
                                          u16* sA, u16* sB, f32x4 (&acc)[4][4]) {
  const int tid   = threadIdx.x;
  const int lane  = tid & 63;
  const int waveM = tid >> 7;
  const int waveN = (tid >> 6) & 1;
  const int lrow  = lane & 15;
  const int lk    = lane >> 4;

  for (int k0 = 0; k0 < K; k0 += 64) {
    __syncthreads();
#pragma unroll
    for (int g = 0; g < 4; g++) {
      int cid = g * 256 + tid;
      int row = cid >> 3;
      int pk  = cid & 7;
      int k16 = pk ^ (row & 7);
      if (A_F32) {
        const float* s = (const float*)Ap + (size_t)(rowBase + row) * lda + k0 + k16 * 8;
        float4 v0 = *(const float4*)s;
        float4 v1 = *(const float4*)(s + 4);
        ushort4 h0, h1;
        h0.x = f2h(v0.x); h0.y = f2h(v0.y); h0.z = f2h(v0.z); h0.w = f2h(v0.w);
        h1.x = f2h(v1.x); h1.y = f2h(v1.y); h1.z = f2h(v1.z); h1.w = f2h(v1.w);
        *(ushort4*)&sA[cid * 8]     = h0;
        *(ushort4*)&sA[cid * 8 + 4] = h1;
      } else {
        uint4 v = *(const uint4*)((const u16*)Ap + (size_t)(rowBase + row) * lda + k0 + k16 * 8);
        *(uint4*)&sA[cid * 8] = v;
      }
      uint4 w = *(const uint4*)(Bt + (size_t)(colBase + row) * ldb + k0 + k16 * 8);
      *(uint4*)&sB[cid * 8] = w;
    }
    __syncthreads();
#pragma unroll
    for (int kk = 0; kk < 2; kk++) {
      f16x8 af[4], bfv[4];
      int k16 = kk * 4 + lk;
#pragma unroll
      for (int mb = 0; mb < 4; mb++) {
        int r = waveM * 64 + mb * 16 + lrow;
        af[mb] = *(const f16x8*)&sA[r * 64 + ((k16 ^ (r & 7)) << 3)];
      }
#pragma unroll
      for (int nb = 0; nb < 4; nb++) {
        int c = waveN * 64 + nb * 16 + lrow;
        bfv[nb] = *(const f16x8*)&sB[c * 64 + ((k16 ^ (c & 7)) << 3)];
      }
#pragma unroll
      for (int mb = 0; mb < 4; mb++)
#pragma unroll
        for (int nb = 0; nb < 4; nb++)
          acc[mb][nb] = __builtin_amdgcn_mfma_f32_16x16x32_f16(af[mb], bfv[nb], acc[mb][nb], 0, 0, 0);
    }
  }
}

// ---------------------------------------------------------------------------
// Projections: z=0..3 -> Q_r,K_r,Q_f,K_f; z=4 -> V=x@Wv+bv (all fp16)
// ---------------------------------------------------------------------------
__global__ __launch_bounds__(256) void k_proj(const u16* __restrict__ xh,
                                              const u16* __restrict__ wt,
                                              u16* __restrict__ qr, u16* __restrict__ kr,
                                              u16* __restrict__ qf, u16* __restrict__ kf,
                                              u16* __restrict__ vh,
                                              const float* __restrict__ bv) {
  __shared__ u16 sA[128 * 64], sB[128 * 64];
  f32x4 acc[4][4] = {};
  const int z = blockIdx.z;
  const int rowBase = blockIdx.y * 128, colBase = blockIdx.x * 128;
  gemm_core<0>(xh, K_D, wt + (size_t)z * 262144, K_D, rowBase, colBase, K_D, sA, sB, acc);

  u16* out = (z == 0) ? qr : (z == 1) ? kr : (z == 2) ? qf : (z == 3) ? kf : vh;
  const int lane = threadIdx.x & 63;
  const int waveM = threadIdx.x >> 7, waveN = (threadIdx.x >> 6) & 1;
  const int lrow = lane & 15, lk = lane >> 4;
#pragma unroll
  for (int mb = 0; mb < 4; mb++)
#pragma unroll
    for (int nb = 0; nb < 4; nb++)
#pragma unroll
      for (int r = 0; r < 4; r++) {
        int grow = rowBase + waveM * 64 + mb * 16 + lk * 4 + r;
        int gcol = colBase + waveN * 64 + nb * 16 + lrow;
        float v = acc[mb][nb][r];
        if (z == 4) v += bv[gcol];
        out[(size_t)grow * K_D + gcol] = f2h(v);
      }
}

// ---------------------------------------------------------------------------
// 8-wave fused dual-branch scores. Wave = 64x32 of the 128x128 tile.
// F16OUT: write fp16 unnormalized scores to outp (u16*), else fp32 (float*).
// USEBITS: masks via packed bitfields, else raw mask arrays + mode flag.
// ---------------------------------------------------------------------------
template <int F16OUT, int USEBITS>
__global__ __launch_bounds__(512, 2) void k_scores8(
    const u16* __restrict__ qr, const u16* __restrict__ kr,
    const u16* __restrict__ qf, const u16* __restrict__ kf,
    const u32* __restrict__ bitR, const u32* __restrict__ bitF,
    const void* __restrict__ mR, const void* __restrict__ mF,
    const int* __restrict__ flag,
    void* __restrict__ outp, float* __restrict__ partial) {

  __shared__ u16 s[2][4][8192];   // [dbuf][Qr,Kr,Qf,Kf][128x64] = 128 KiB

  const int tid = threadIdx.x;
  const int lane = tid & 63, wid = tid >> 6;
  const int bx = blockIdx.x, by = blockIdx.y;
  const int rowBase = by * 128, colBase = bx * 128;

  const u16* base0 = qr + (size_t)rowBase * K_D;
  const u16* base1 = kr + (size_t)colBase * K_D;
  const u16* base2 = qf + (size_t)rowBase * K_D;
  const u16* base3 = kf + (size_t)colBase * K_D;

  f32x4 accR[4][2] = {}, accF[4][2] = {};

  auto STAGE = [&](int b, int k0) {
    const u16* bases[4] = {base0, base1, base2, base3};
#pragma unroll
    for (int t = 0; t < 4; ++t)
#pragma unroll
      for (int j = 0; j < 2; ++j) {
        int cid = j * 512 + tid;          // 16B chunk id, 0..1023
        int row = cid >> 3;
        int k16 = (cid & 7) ^ (row & 7);  // swizzled source -> linear LDS
        gload_lds16(bases[t] + (size_t)row * K_D + k0 + k16 * 8,
                    &s[b][t][(j * 512 + wid * 64) * 8]);
      }
  };

  STAGE(0, 0);
  __syncthreads();

  const int waveM = wid >> 2;         // 0..1  (64 rows)
  const int waveN = wid & 3;          // 0..3  (32 cols)
  const int lrow = lane & 15, lk = lane >> 4;

  int cur = 0;
  for (int it = 0; it < 8; ++it) {
    if (it < 7) STAGE(cur ^ 1, (it + 1) * 64);
#pragma unroll
    for (int kk = 0; kk < 2; ++kk) {
      int k16 = kk * 4 + lk;
      f16x8 aR[4], aF[4], bR[2], bF[2];
#pragma unroll
      for (int mb = 0; mb < 4; ++mb) {
        int r = waveM * 64 + mb * 16 + lrow;
        int off = r * 64 + ((k16 ^ (r & 7)) << 3);
        aR[mb] = *(const f16x8*)&s[cur][0][off];
        aF[mb] = *(const f16x8*)&s[cur][2][off];
      }
#pragma unroll
      for (int nb = 0; nb < 2; ++nb) {
        int c = waveN * 32 + nb * 16 + lrow;
        int off = c * 64 + ((k16 ^ (c & 7)) << 3);
        bR[nb] = *(const f16x8*)&s[cur][1][off];
        bF[nb] = *(const f16x8*)&s[cur][3][off];
      }
#pragma unroll
      for (int mb = 0; mb < 4; ++mb)
#pragma unroll
        for (int nb = 0; nb < 2; ++nb) {
          accR[mb][nb] = __builtin_amdgcn_mfma_f32_16x16x32_f16(aR[mb], bR[nb], accR[mb][nb], 0, 0, 0);
          accF[mb][nb] = __builtin_amdgcn_mfma_f32_16x16x32_f16(aF[mb], bF[nb], accF[mb][nb], 0, 0, 0);
        }
    }
    __syncthreads();
    cur ^= 1;
  }

  // ---- epilogue: masked exp, rowsum partials, coalesced store via LDS ----
  const float scale = 0.04419417382415922f;   // 1/sqrt(512)
  const int mode = USEBITS ? 0 : *flag;
  u16*   vt16 = (u16*)&s[0][0][0];            // [128][136] fp16 restage
  float* vt32 = (float*)&s[0][0][0];          // [128][132] fp32 restage

#pragma unroll
  for (int mb = 0; mb < 4; ++mb)
#pragma unroll
    for (int rr = 0; rr < 4; ++rr) {
      int growl = waveM * 64 + mb * 16 + lk * 4 + rr;
      int grow = rowBase + growl;
      u32 wR = 0, wF = 0;
      if (USEBITS) {
        wR = bitR[(size_t)grow * 256 + bx * 4 + waveN];
        wF = bitF[(size_t)grow * 256 + bx * 4 + waveN];
      }
      float rs = 0.f;
#pragma unroll
      for (int nb = 0; nb < 2; ++nb) {
        int bitpos = nb * 16 + lrow;
        int gcoll = waveN * 32 + bitpos;
        bool m1, m2;
        if (USEBITS) {
          m1 = (wR >> bitpos) & 1u;
          m2 = (wF >> bitpos) & 1u;
        } else {
          size_t oi = (size_t)grow * K_N + colBase + gcoll;
          m1 = mask_at(mR, mode, oi);
          m2 = mask_at(mF, mode, oi);
        }
        float er = m1 ? 0.f : __expf(accR[mb][nb][rr] * scale);
        float ef = m2 ? 0.f : __expf(accF[mb][nb][rr] * scale);
        float v = er + 0.5f * ef;
        rs += v;
        if (F16OUT) vt16[growl * 136 + gcoll] = f2h(v);
        else        vt32[growl * 132 + gcoll] = v;
      }
      rs += __shfl_xor(rs, 1, 64);
      rs += __shfl_xor(rs, 2, 64);
      rs += __shfl_xor(rs, 4, 64);
      rs += __shfl_xor(rs, 8, 64);
      if (lrow == 0)
        partial[(size_t)grow * 256 + bx * 4 + waveN] = rs;
    }
  __syncthreads();

  if (F16OUT) {
    u16* out = (u16*)outp;
#pragma unroll
    for (int j = 0; j < 4; ++j) {
      int f = j * 512 + tid;            // 16B unit in 128x128 fp16 tile
      int row = f >> 4, seg = f & 15;
      uint4 v = *(const uint4*)&vt16[row * 136 + seg * 8];
      *(uint4*)&out[(size_t)(rowBase + row) * K_N + colBase + seg * 8] = v;
    }
  } else {
    float* out = (float*)outp;
#pragma unroll
    for (int j = 0; j < 8; ++j) {
      int f = j * 512 + tid;            // float4 unit in 128x128 fp32 tile
      int row = f >> 5, seg = f & 31;
      float4 v = *(const float4*)&vt32[row * 132 + seg * 4];
      *(float4*)&out[(size_t)(rowBase + row) * K_N + colBase + seg * 4] = v;
    }
  }
}

// ---------------------------------------------------------------------------
__global__ void k_rowsum(const float* __restrict__ partial, float* __restrict__ inv) {
  int r = blockIdx.x * 256 + threadIdx.x;
  const float4* p = (const float4*)(partial + (size_t)r * 256);
  float s = 0.f;
#pragma unroll 8
  for (int j = 0; j < 64; j++) {
    float4 v = p[j];
    s += v.x + v.y + v.z + v.w;
  }
  inv[r] = 1.0f / s;
}

// norm (fp16 scratch -> fp32 attn)
__global__ void k_norm_a(const u16* __restrict__ sh, const float* __restrict__ inv,
                         float* __restrict__ attn) {
  const size_t total = (size_t)K_N * K_N / 8;      // 8-elem chunks
  for (size_t i = (size_t)blockIdx.x * 256 + threadIdx.x; i < total;
       i += (size_t)gridDim.x * 256) {
    int row = (int)(i >> 10);                      // 1024 chunks per row
    float s = inv[row];
    uint4 v = ((const uint4*)sh)[i];
    float4 o0, o1;
    o0.x = h2f(v.x & 0xFFFF) * s; o0.y = h2f(v.x >> 16) * s;
    o0.z = h2f(v.y & 0xFFFF) * s; o0.w = h2f(v.y >> 16) * s;
    o1.x = h2f(v.z & 0xFFFF) * s; o1.y = h2f(v.z >> 16) * s;
    o1.z = h2f(v.w & 0xFFFF) * s; o1.w = h2f(v.w >> 16) * s;
    ((float4*)attn)[2 * i]     = o0;
    ((float4*)attn)[2 * i + 1] = o1;
  }
}

// norm in place (fp32 attn)
__global__ void k_norm_b(float* __restrict__ attn, const float* __restrict__ inv) {
  const size_t total = (size_t)K_N * K_N / 4;
  for (size_t i = (size_t)blockIdx.x * 256 + threadIdx.x; i < total;
       i += (size_t)gridDim.x * 256) {
    int row = (int)(i >> 11);
    float s = inv[row];
    float4 v = ((float4*)attn)[i];
    v.x *= s; v.y *= s; v.z *= s; v.w *= s;
    ((float4*)attn)[i] = v;
  }
}

// ---------------------------------------------------------------------------
// cntx = (unnormalized scores * inv[row]) @ V.  A is fp16 scratch (A_F32=0)
// or fp32 attn (A_F32=1). XCD-chunked block swizzle for attn L2 locality.
// ---------------------------------------------------------------------------
template <int A_F32>
__global__ __launch_bounds__(256) void k_cntx(const void* __restrict__ Ap,
                                              const u16* __restrict__ vT,
                                              const float* __restrict__ inv,
                                              float* __restrict__ out) {
  __shared__ u16 sA[128 * 64], sB[128 * 64];
  f32x4 acc[4][4] = {};
  int b = blockIdx.x + blockIdx.y * 4;
  int c = b & 7, jj = b >> 3;
  int xb = jj & 3, yb = c + 8 * (jj >> 2);
  const int rowBase = yb * 128, colBase = xb * 128;
  gemm_core<A_F32>(Ap, K_N, vT, K_N, rowBase, colBase, K_N, sA, sB, acc);

  const int lane = threadIdx.x & 63;
  const int waveM = threadIdx.x >> 7, waveN = (threadIdx.x >> 6) & 1;
  const int lrow = lane & 15, lk = lane >> 4;
#pragma unroll
  for (int mb = 0; mb < 4; mb++)
#pragma unroll
    for (int r = 0; r < 4; r++) {
      int grow = rowBase + waveM * 64 + mb * 16 + lk * 4 + r;
      float iv = inv[grow];
#pragma unroll
      for (int nb = 0; nb < 4; nb++) {
        int gcol = colBase + waveN * 64 + nb * 16 + lrow;
        out[(size_t)grow * K_D + gcol] = acc[mb][nb][r] * iv;
      }
    }
}

// ---------------------------------------------------------------------------
extern "C" void kernel_launch(void* const* d_in, const int* in_sizes, int n_in,
                              void* d_out, int out_size, void* d_ws, size_t ws_size,
                              hipStream_t stream) {
  const float* x   = (const float*)d_in[0];
  const void*  mR  = d_in[1];
  const void*  mF  = d_in[2];
  const float* Wv  = (const float*)d_in[7];
  const float* bv  = (const float*)d_in[8];

  const size_t ND = (size_t)K_N * K_D;     // 4M elems
  u16* xh = (u16*)d_ws;                    // 8 MB each
  u16* qr = xh + ND;
  u16* kr = qr + ND;
  u16* qf = kr + ND;
  u16* kf = qf + ND;
  u16* vh = kf + ND;
  u16* vT = vh + ND;
  u16* wt = vT + ND;                       // 5 * 512*512 fp16 = 2.5 MB
  u32* bitR = (u32*)(wt + 5 * 262144);     // 8 MB
  u32* bitF = bitR + (size_t)K_N * 256;    // 8 MB
  u16* sh   = (u16*)(bitF + (size_t)K_N * 256);  // fp16 scores scratch, 128 MB

  const size_t need_bits = (size_t)((u16*)bitR - (u16*)d_ws) * 2 + 2 * 8388608;
  const size_t need_sh   = (size_t)((char*)sh - (char*)d_ws) + (size_t)K_N * K_N * 2;
  const bool have_bits = ws_size >= need_bits;
  const bool have_sh   = ws_size >= need_sh;

  float* cntx = (float*)d_out;
  float* attn = cntx + ND;
  // partial overlays xh (dead after k_proj); inv overlays qr (dead after scores)
  float* partial = (float*)d_ws;                 // [8192][256] = 8 MB
  float* inv     = (float*)qr;                   // [8192]
  int*   flag    = (int*)cntx;                   // cntx written last

  k_detect<<<1, 256, 0, stream>>>((const unsigned char*)mR, flag);
  if (have_bits)
    k_packmask<<<2048, 256, 0, stream>>>(mR, mF, flag, bitR, bitF);

  k_cvt_x<<<4096, 256, 0, stream>>>(x, xh);
  k_transpose<1><<<dim3(8, 8), 256, 0, stream>>>((const void*)d_in[3], wt + 0 * 262144, 512, 512);
  k_transpose<1><<<dim3(8, 8), 256, 0, stream>>>((const void*)d_in[4], wt + 1 * 262144, 512, 512);
  k_transpose<1><<<dim3(8, 8), 256, 0, stream>>>((const void*)d_in[5], wt + 2 * 262144, 512, 512);
  k_transpose<1><<<dim3(8, 8), 256, 0, stream>>>((const void*)d_in[6], wt + 3 * 262144, 512, 512);
  k_transpose<1><<<dim3(8, 8), 256, 0, stream>>>(Wv,  wt + 4 * 262144, 512, 512);

  k_proj<<<dim3(4, 64, 5), 256, 0, stream>>>(xh, wt, qr, kr, qf, kf, vh, bv);
  k_transpose<0><<<dim3(8, 128), 256, 0, stream>>>(vh, vT, K_N, K_D);

  if (have_sh && have_bits) {
    k_scores8<1, 1><<<dim3(64, 64), 512, 0, stream>>>(qr, kr, qf, kf, bitR, bitF,
                                                      mR, mF, flag, sh, partial);
    k_rowsum<<<32, 256, 0, stream>>>(partial, inv);
    k_cntx<0><<<dim3(4, 64), 256, 0, stream>>>(sh, vT, inv, cntx);
    k_norm_a<<<2048, 256, 0, stream>>>(sh, inv, attn);
  } else if (have_bits) {
    k_scores8<0, 1><<<dim3(64, 64), 512, 0, stream>>>(qr, kr, qf, kf, bitR, bitF,
                                                      mR, mF, flag, attn, partial);
    k_rowsum<<<32, 256, 0, stream>>>(partial, inv);
    k_cntx<1><<<dim3(4, 64), 256, 0, stream>>>(attn, vT, inv, cntx);
    k_norm_b<<<8192, 256, 0, stream>>>(attn, inv);
  } else {
    k_scores8<0, 0><<<dim3(64, 64), 512, 0, stream>>>(qr, kr, qf, kf, nullptr, nullptr,
                                                      mR, mF, flag, attn, partial);
    k_rowsum<<<32, 256, 0, stream>>>(partial, inv);
    k_cntx<1><<<dim3(4, 64), 256, 0, stream>>>(attn, vT, inv, cntx);
    k_norm_b<<<8192, 256, 0, stream>>>(attn, inv);
  }
}